// Round 2
// baseline (490.192 us; speedup 1.0000x reference)
//
#include <hip/hip_runtime.h>
#include <math.h>
#include <stddef.h>

#define HQ   16
#define HKV  8
#define DH   128
#define HID  2048
#define CC   16384
#define NCH  64             // flash chunks of 256: 64*256 = 16384 = CC
#define CHUNK 256

// d_out layout (FLOAT32, 4096 elements): [attn 2048][k_new 8*128][v 8*128]
//
// ws layout (floats):
//   qf      @ 0      (2048)   q normed+roped   [HQ][DH]
//   kf      @ 2048   (1024)   k normed+roped   [HKV][DH]
//   vnew    @ 3072   (1024)   v new token      [HKV][DH]
//   attn_in @ 4096   (2048)   attention output [HQ][DH]
//   opart   @ 6144   (131072) partial O        [HQ][NCH][DH]
//   ML      @ 137216 (2048)   (m,l) per chunk  [HQ][NCH] float2
//   ctr     @ 139264 (16 ints) sync counters: [0..7]=per-kv, [8]=combines done

// ---- K_A: fused QKV projection + RMSNorm + RoPE. grid=32 x 1024 threads.
// Block b: b<16 -> q head b; b<24 -> k head b-16; else v head b-24.
// Each wave computes 8 output dims with fully-coalesced row reads.
__global__ __launch_bounds__(1024) void k_qkvnorm(
    const float* __restrict__ x,
    const float* __restrict__ Wq,
    const float* __restrict__ Wk,
    const float* __restrict__ Wv,
    const float* __restrict__ cosb,
    const float* __restrict__ sinb,
    const float* __restrict__ qw,
    const float* __restrict__ kw,
    float* __restrict__ qf,
    float* __restrict__ kf,
    float* __restrict__ vnew,
    float* __restrict__ out,
    int* __restrict__ ctr){
  __shared__ float xs[HID];        // 8 KB staged input row
  __shared__ float rowval[DH];
  __shared__ float wsum[2];
  __shared__ float normed[DH];
  int b = blockIdx.x, t = threadIdx.x;
  if (b == 0 && t < 16) ctr[t] = 0;      // reset sync counters for K_B
  xs[t] = x[t];
  xs[t + 1024] = x[t + 1024];
  __syncthreads();

  bool isq = (b < 16), isk = (b >= 16 && b < 24);
  int h = isq ? b : (isk ? b - 16 : b - 24);
  const float* W = isq ? Wq : (isk ? Wk : Wv);
  W += (size_t)h * DH * HID;

  int w = t >> 6, l = t & 63;      // 16 waves, each owns 8 output dims
  float vals[8];
  #pragma unroll
  for (int oo = 0; oo < 8; ++oo){
    const float* Wr = W + (size_t)(w * 8 + oo) * HID;
    float acc = 0.f;
    #pragma unroll
    for (int j = 0; j < 8; ++j){
      int idx = (j * 64 + l) * 4;
      float4 wf = *(const float4*)(Wr + idx);
      float4 xf = *(const float4*)(xs + idx);
      acc += wf.x*xf.x + wf.y*xf.y + wf.z*xf.z + wf.w*xf.w;
    }
    vals[oo] = acc;
  }
  #pragma unroll
  for (int oo = 0; oo < 8; ++oo){
    float acc = vals[oo];
    #pragma unroll
    for (int off = 32; off; off >>= 1) acc += __shfl_down(acc, off, 64);
    if (l == 0) rowval[w * 8 + oo] = acc;
  }
  __syncthreads();

  float val = (t < DH) ? rowval[t] : 0.f;
  if (!isq && !isk){
    // v head: passthrough to d_out + workspace for combine
    if (t < DH){
      out[3072 + h * DH + t] = val;
      vnew[h * DH + t] = val;
    }
    return;
  }
  // rmsnorm over the 128-dim row
  float ss = val * val;
  if (t < DH){
    #pragma unroll
    for (int off = 32; off; off >>= 1) ss += __shfl_down(ss, off, 64);
    if ((t & 63) == 0) wsum[t >> 6] = ss;
  }
  __syncthreads();
  float rms = sqrtf((wsum[0] + wsum[1]) * (1.f / 128.f) + 1e-6f);
  if (t < DH){
    float wgt = isq ? qw[t] : kw[t];
    normed[t] = val / rms * wgt;
  }
  __syncthreads();
  if (t < DH){
    float nv = normed[t];
    float rot = (t < 64) ? -normed[t + 64] : normed[t - 64];
    float res = nv * cosb[t] + rot * sinb[t];
    if (isq) qf[h * DH + t] = res;
    else { kf[h * DH + t] = res; out[2048 + h * DH + t] = res; }
  }
}

// ---- K_B: flash chunks + last-block combine + grid sync + o_proj, one launch.
// grid = HKV*NCH = 512 blocks x 256 threads; launch_bounds guarantees >=2
// blocks/CU so all 512 are co-resident (spin-wait is safe).
__global__ __launch_bounds__(256, 2) void k_attn(
    const float* __restrict__ qf,
    const float* __restrict__ kf,
    const float* __restrict__ vnew,
    const float* __restrict__ kcache,   // [HKV][DH][CC]
    const float* __restrict__ vcache,   // [HKV][CC][DH]
    const float* __restrict__ mask,     // [CC+1]
    const float* __restrict__ Wo,
    float* __restrict__ opart,          // [HQ][NCH][DH]
    float2* __restrict__ ml,            // [HQ][NCH]
    float* __restrict__ attn_in,        // [HQ][DH]
    int* __restrict__ ctr,
    float* __restrict__ out){
  __shared__ float q_s[2][DH];
  __shared__ float sc_part[4][2][CHUNK];
  __shared__ float p_s[2][CHUNK];
  __shared__ float part[2][8][DH];
  __shared__ float red[8];
  __shared__ int lastFlag;
  int kv = blockIdx.x >> 6, ch = blockIdx.x & 63;
  int c0 = ch << 8;
  int t = threadIdx.x;
  q_s[t >> 7][t & 127] = qf[(kv * 2 + (t >> 7)) * DH + (t & 127)];
  __syncthreads();
  const float scale = 0.08838834764831845f;  // 128^-0.5

  // ---- Phase A: QK^T. Thread (dg, ln): 4 consecutive positions, 32 dims.
  {
    int dg = t >> 6, ln = t & 63;
    const float* kp = kcache + (size_t)kv * DH * CC + (size_t)(dg * 32) * CC + (c0 + ln * 4);
    float a00 = 0.f, a01 = 0.f, a02 = 0.f, a03 = 0.f;
    float a10 = 0.f, a11 = 0.f, a12 = 0.f, a13 = 0.f;
    #pragma unroll 8
    for (int dd = 0; dd < 32; ++dd){
      float4 kk = *(const float4*)(kp + (size_t)dd * CC);
      float q0 = q_s[0][dg * 32 + dd], q1 = q_s[1][dg * 32 + dd];
      a00 += q0 * kk.x; a01 += q0 * kk.y; a02 += q0 * kk.z; a03 += q0 * kk.w;
      a10 += q1 * kk.x; a11 += q1 * kk.y; a12 += q1 * kk.z; a13 += q1 * kk.w;
    }
    *(float4*)&sc_part[dg][0][ln * 4] = make_float4(a00, a01, a02, a03);
    *(float4*)&sc_part[dg][1][ln * 4] = make_float4(a10, a11, a12, a13);
  }
  __syncthreads();

  // ---- Phase B: combine partial dots, chunk softmax (m, l).
  float s0, s1;
  {
    float mk = mask[c0 + t];
    s0 = (sc_part[0][0][t] + sc_part[1][0][t] + sc_part[2][0][t] + sc_part[3][0][t]) * scale + mk;
    s1 = (sc_part[0][1][t] + sc_part[1][1][t] + sc_part[2][1][t] + sc_part[3][1][t]) * scale + mk;
  }
  int wv = t >> 6, ln = t & 63;
  float lmax0 = s0, lmax1 = s1;
  #pragma unroll
  for (int off = 32; off; off >>= 1){
    lmax0 = fmaxf(lmax0, __shfl_down(lmax0, off, 64));
    lmax1 = fmaxf(lmax1, __shfl_down(lmax1, off, 64));
  }
  if (ln == 0){ red[wv] = lmax0; red[4 + wv] = lmax1; }
  __syncthreads();
  float m0 = fmaxf(fmaxf(red[0], red[1]), fmaxf(red[2], red[3]));
  float m1 = fmaxf(fmaxf(red[4], red[5]), fmaxf(red[6], red[7]));
  float p0 = __expf(s0 - m0);
  float p1 = __expf(s1 - m1);
  p_s[0][t] = p0;
  p_s[1][t] = p1;
  float ls0 = p0, ls1 = p1;
  #pragma unroll
  for (int off = 32; off; off >>= 1){
    ls0 += __shfl_down(ls0, off, 64);
    ls1 += __shfl_down(ls1, off, 64);
  }
  __syncthreads();
  if (ln == 0){ red[wv] = ls0; red[4 + wv] = ls1; }
  __syncthreads();
  if (t == 0){
    float l0 = red[0] + red[1] + red[2] + red[3];
    float l1 = red[4] + red[5] + red[6] + red[7];
    ml[(size_t)(kv * 2)     * NCH + ch] = make_float2(m0, l0);
    ml[(size_t)(kv * 2 + 1) * NCH + ch] = make_float2(m1, l1);
  }

  // ---- Phase C: partial O = sum_c p[c]*V[c][:].
  {
    int sl = t >> 5, d4 = (t & 31) * 4;
    const float* vbase = vcache + (size_t)kv * CC * DH + d4;
    float4 a0 = make_float4(0.f, 0.f, 0.f, 0.f);
    float4 a1 = make_float4(0.f, 0.f, 0.f, 0.f);
    #pragma unroll 4
    for (int i = 0; i < 32; ++i){
      int off = i * 8 + sl;
      float pp0 = p_s[0][off];
      float pp1 = p_s[1][off];
      float4 v = *(const float4*)(vbase + (size_t)(c0 + off) * DH);
      a0.x += pp0 * v.x; a0.y += pp0 * v.y; a0.z += pp0 * v.z; a0.w += pp0 * v.w;
      a1.x += pp1 * v.x; a1.y += pp1 * v.y; a1.z += pp1 * v.z; a1.w += pp1 * v.w;
    }
    *(float4*)&part[0][sl][d4] = a0;
    *(float4*)&part[1][sl][d4] = a1;
  }
  __syncthreads();
  {
    int hh = t >> 7, d = t & 127;
    float o = 0.f;
    #pragma unroll
    for (int ss = 0; ss < 8; ++ss) o += part[hh][ss][d];
    int qh = kv * 2 + hh;
    opart[((size_t)qh * NCH + ch) * DH + d] = o;
  }

  // ---- signal chunk done; last block per kv does the combine
  __threadfence();
  __syncthreads();
  if (t == 0) lastFlag = (atomicAdd(&ctr[kv], 1) == NCH - 1) ? 1 : 0;
  __syncthreads();
  if (lastFlag){
    __threadfence();   // acquire: see all chunks' opart/ml
    int h = t >> 7, d = t & 127;
    int qh = kv * 2 + h;
    const float2* mlrow = ml + (size_t)qh * NCH;
    float M = -1e30f;
    #pragma unroll 8
    for (int c = 0; c < NCH; ++c) M = fmaxf(M, mlrow[c].x);
    float oacc = 0.f, L = 0.f;
    #pragma unroll 4
    for (int c = 0; c < NCH; ++c){
      float2 m2 = mlrow[c];
      float wgt = __expf(m2.x - M);
      L += m2.y * wgt;
      oacc += wgt * opart[((size_t)qh * NCH + c) * DH + d];
    }
    // new-token score: q . k_new, reduced over the 128 threads of this head
    float prod = qf[qh * DH + d] * kf[kv * DH + d];
    #pragma unroll
    for (int off = 32; off; off >>= 1) prod += __shfl_down(prod, off, 64);
    if ((t & 63) == 0) red[t >> 6] = prod;
    __syncthreads();
    float s_new = (red[h * 2] + red[h * 2 + 1]) * scale + mask[CC];
    float pn = __expf(s_new - M);
    L += pn;
    oacc += pn * vnew[kv * DH + d];
    attn_in[qh * DH + d] = oacc / L;
    __threadfence();
    __syncthreads();
    if (t == 0) atomicAdd(&ctr[8], 1);
  }

  // ---- grid-wide wait: all 8 combines done (all blocks co-resident)
  if (t == 0){
    while (__hip_atomic_load(&ctr[8], __ATOMIC_ACQUIRE, __HIP_MEMORY_SCOPE_AGENT) < HKV){
      __builtin_amdgcn_s_sleep(2);
    }
  }
  __syncthreads();
  __threadfence();

  // ---- o_proj: one wave per output element, e in [0,2048)
  {
    int wv2 = t >> 6, l2 = t & 63;
    int e = blockIdx.x * 4 + wv2;
    const float* Wr = Wo + (size_t)e * HID;
    float acc = 0.f;
    #pragma unroll
    for (int j = 0; j < 4; ++j){
      int base = (j * 64 + l2) * 8;
      float4 a0 = *(const float4*)(attn_in + base);
      float4 a1 = *(const float4*)(attn_in + base + 4);
      float4 b0 = *(const float4*)(Wr + base);
      float4 b1 = *(const float4*)(Wr + base + 4);
      acc += a0.x*b0.x + a0.y*b0.y + a0.z*b0.z + a0.w*b0.w
           + a1.x*b1.x + a1.y*b1.y + a1.z*b1.z + a1.w*b1.w;
    }
    #pragma unroll
    for (int off = 32; off; off >>= 1) acc += __shfl_down(acc, off, 64);
    if (l2 == 0) out[e] = acc;
  }
}

extern "C" void kernel_launch(void* const* d_in, const int* in_sizes, int n_in,
                              void* d_out, int out_size, void* d_ws, size_t ws_size,
                              hipStream_t stream){
  const float* x    = (const float*)d_in[0];
  const float* cosb = (const float*)d_in[1];
  const float* sinb = (const float*)d_in[2];
  const float* mask = (const float*)d_in[3];
  const float* kc   = (const float*)d_in[4];
  const float* vc   = (const float*)d_in[5];
  const float* Wq   = (const float*)d_in[6];
  const float* Wk   = (const float*)d_in[7];
  const float* Wv   = (const float*)d_in[8];
  const float* Wo   = (const float*)d_in[9];
  const float* qw   = (const float*)d_in[10];
  const float* kw   = (const float*)d_in[11];
  float* out = (float*)d_out;
  float* ws = (float*)d_ws;
  float* qf      = ws;                      // 2048
  float* kf      = ws + 2048;               // 1024
  float* vnew    = ws + 3072;               // 1024
  float* attn_in = ws + 4096;               // 2048
  float* opart   = ws + 6144;               // 16*64*128 = 131072
  float2* ML     = (float2*)(ws + 137216);  // 16*64 float2 = 2048 floats
  int*   ctr     = (int*)(ws + 139264);     // 16 ints

  k_qkvnorm<<<32, 1024, 0, stream>>>(x, Wq, Wk, Wv, cosb, sinb, qw, kw,
                                     qf, kf, vnew, out, ctr);
  k_attn<<<HKV * NCH, 256, 0, stream>>>(qf, kf, vnew, kc, vc, mask, Wo,
                                        opart, ML, attn_in, ctr, out);
}

// Round 3
// 216.321 us; speedup vs baseline: 2.2660x; 2.2660x over previous
//
#include <hip/hip_runtime.h>
#include <math.h>
#include <stddef.h>

#define HQ   16
#define HKV  8
#define DH   128
#define HID  2048
#define CC   16384
#define NCH  128            // flash chunks of 128
#define CHUNK 128

// d_out layout (FLOAT32, 4096 elements): [attn 2048][k_new 8*128][v 8*128]

// ---- K1: QKV projections. One wave per output element.
// Explicit 8-deep register batching of the W row stream (VGPR-starved before).
__global__ void k_qkv(const float* __restrict__ x,
                      const float* __restrict__ Wq,
                      const float* __restrict__ Wk,
                      const float* __restrict__ Wv,
                      float* __restrict__ raw,
                      float* __restrict__ out){
  int wave = threadIdx.x >> 6, lane = threadIdx.x & 63;
  int e = blockIdx.x * 4 + wave;
  const float* W;
  if (e < 2048)      W = Wq + (size_t)e * HID;
  else if (e < 3072) W = Wk + (size_t)(e - 2048) * HID;
  else               W = Wv + (size_t)(e - 3072) * HID;
  float4 wb[8], xb[8];
  #pragma unroll
  for (int j = 0; j < 8; ++j) wb[j] = *(const float4*)(W + (j * 64 + lane) * 4);
  #pragma unroll
  for (int j = 0; j < 8; ++j) xb[j] = *(const float4*)(x + (j * 64 + lane) * 4);
  float acc = 0.f;
  #pragma unroll
  for (int j = 0; j < 8; ++j)
    acc += wb[j].x*xb[j].x + wb[j].y*xb[j].y + wb[j].z*xb[j].z + wb[j].w*xb[j].w;
  #pragma unroll
  for (int off = 32; off; off >>= 1) acc += __shfl_down(acc, off, 64);
  if (lane == 0){
    raw[e] = acc;
    if (e >= 3072) out[e] = acc;   // v passthrough
  }
}

// ---- K2: RMSNorm + RoPE (q,k). grid=24, 128 threads.
__global__ void k_normrope(const float* __restrict__ raw,
                           const float* __restrict__ cosb,
                           const float* __restrict__ sinb,
                           const float* __restrict__ qw,
                           const float* __restrict__ kw,
                           float* __restrict__ qf,
                           float* __restrict__ kf,
                           float* __restrict__ out){
  __shared__ float lds[DH];
  __shared__ float wsum[2];
  int b = blockIdx.x, t = threadIdx.x;
  bool isq = (b < 16);
  int h = isq ? b : b - 16;
  float val = isq ? raw[h * DH + t] : raw[2048 + h * DH + t];
  float ss = val * val;
  #pragma unroll
  for (int off = 32; off; off >>= 1) ss += __shfl_down(ss, off, 64);
  if ((t & 63) == 0) wsum[t >> 6] = ss;
  __syncthreads();
  float rms = sqrtf((wsum[0] + wsum[1]) / 128.f + 1e-6f);
  float w = isq ? qw[t] : kw[t];
  float normed = val / rms * w;
  lds[t] = normed;
  __syncthreads();
  float rot = (t < 64) ? -lds[t + 64] : lds[t - 64];
  float res = normed * cosb[t] + rot * sinb[t];
  if (isq) qf[h * DH + t] = res;
  else { kf[h * DH + t] = res; out[2048 + h * DH + t] = res; }
}

// ---- K3: flash-decode chunk kernel. grid = HKV*NCH = 1024, 256 threads.
// Explicit 8-deep float4 register batches in BOTH streaming phases; first
// V batch issued before the softmax phase so its latency hides under B.
__global__ __launch_bounds__(256, 4) void k_flash(
    const float* __restrict__ qf,
    const float* __restrict__ kcache,  // [HKV][DH][CC]
    const float* __restrict__ vcache,  // [HKV][CC][DH]
    const float* __restrict__ mask,    // [CC+1]
    float* __restrict__ opart,         // [HQ][NCH][DH]
    float2* __restrict__ ml){          // [HQ][NCH]
  __shared__ float q_s[2][DH];
  __shared__ float sc_part[8][2][CHUNK];
  __shared__ float p_s[2][CHUNK];
  __shared__ float part[2][8][DH];
  __shared__ float red[8];
  int kv = blockIdx.x >> 7, ch = blockIdx.x & 127;
  int c0 = ch << 7;
  int t = threadIdx.x;
  q_s[t >> 7][t & 127] = qf[(kv * 2 + (t >> 7)) * DH + (t & 127)];
  __syncthreads();
  const float scale = 0.08838834764831845f;  // 128^-0.5

  // ---- Phase A: QK^T. Thread (dg, ln): 4 consecutive positions, 16 dims.
  {
    int dg = t >> 5, ln = t & 31;
    const float* kp = kcache + (size_t)kv * DH * CC + (size_t)(dg * 16) * CC + (c0 + ln * 4);
    float4 k0[8], k1[8];
    #pragma unroll
    for (int j = 0; j < 8; ++j) k0[j] = *(const float4*)(kp + (size_t)j * CC);
    #pragma unroll
    for (int j = 0; j < 8; ++j) k1[j] = *(const float4*)(kp + (size_t)(j + 8) * CC);
    float a00 = 0.f, a01 = 0.f, a02 = 0.f, a03 = 0.f;
    float a10 = 0.f, a11 = 0.f, a12 = 0.f, a13 = 0.f;
    #pragma unroll
    for (int j = 0; j < 8; ++j){
      float q0 = q_s[0][dg * 16 + j], q1 = q_s[1][dg * 16 + j];
      a00 += q0 * k0[j].x; a01 += q0 * k0[j].y; a02 += q0 * k0[j].z; a03 += q0 * k0[j].w;
      a10 += q1 * k0[j].x; a11 += q1 * k0[j].y; a12 += q1 * k0[j].z; a13 += q1 * k0[j].w;
    }
    #pragma unroll
    for (int j = 0; j < 8; ++j){
      float q0 = q_s[0][dg * 16 + 8 + j], q1 = q_s[1][dg * 16 + 8 + j];
      a00 += q0 * k1[j].x; a01 += q0 * k1[j].y; a02 += q0 * k1[j].z; a03 += q0 * k1[j].w;
      a10 += q1 * k1[j].x; a11 += q1 * k1[j].y; a12 += q1 * k1[j].z; a13 += q1 * k1[j].w;
    }
    *(float4*)&sc_part[dg][0][ln * 4] = make_float4(a00, a01, a02, a03);
    *(float4*)&sc_part[dg][1][ln * 4] = make_float4(a10, a11, a12, a13);
  }
  __syncthreads();

  // ---- Early V batch 1: issue loads now; latency hides under Phase B.
  int sl = t >> 5, d4 = (t & 31) * 4;
  const float* vbase = vcache + (size_t)kv * CC * DH + (size_t)c0 * DH + d4;
  float4 vv0[8];
  #pragma unroll
  for (int j = 0; j < 8; ++j)
    vv0[j] = *(const float4*)(vbase + (size_t)(j * 8 + sl) * DH);

  // ---- Phase B: combine partials, chunk softmax. Thread (h, pos).
  int h = t >> 7, pos = t & 127;
  float s;
  {
    float acc = 0.f;
    #pragma unroll
    for (int dg = 0; dg < 8; ++dg) acc += sc_part[dg][h][pos];
    s = acc * scale + mask[c0 + pos];
  }
  int wv = t >> 6;
  float lm = s;
  #pragma unroll
  for (int off = 32; off; off >>= 1) lm = fmaxf(lm, __shfl_down(lm, off, 64));
  if ((t & 63) == 0) red[wv] = lm;
  __syncthreads();
  float m = fmaxf(red[h * 2], red[h * 2 + 1]);
  float p = __expf(s - m);
  p_s[h][pos] = p;
  float lsum = p;
  #pragma unroll
  for (int off = 32; off; off >>= 1) lsum += __shfl_down(lsum, off, 64);
  if ((t & 63) == 0) red[4 + wv] = lsum;
  __syncthreads();
  if ((t & 127) == 0){
    float l = red[4 + h * 2] + red[5 + h * 2];
    ml[(size_t)(kv * 2 + h) * NCH + ch] = make_float2(m, l);
  }

  // ---- Phase C: partial O. Batch 1 already in flight; batch 2 behind it.
  {
    float4 vv1[8];
    #pragma unroll
    for (int j = 0; j < 8; ++j)
      vv1[j] = *(const float4*)(vbase + (size_t)((j + 8) * 8 + sl) * DH);
    float4 a0 = make_float4(0.f, 0.f, 0.f, 0.f);
    float4 a1 = make_float4(0.f, 0.f, 0.f, 0.f);
    #pragma unroll
    for (int j = 0; j < 8; ++j){
      int off = j * 8 + sl;
      float pp0 = p_s[0][off], pp1 = p_s[1][off];
      a0.x += pp0 * vv0[j].x; a0.y += pp0 * vv0[j].y; a0.z += pp0 * vv0[j].z; a0.w += pp0 * vv0[j].w;
      a1.x += pp1 * vv0[j].x; a1.y += pp1 * vv0[j].y; a1.z += pp1 * vv0[j].z; a1.w += pp1 * vv0[j].w;
    }
    #pragma unroll
    for (int j = 0; j < 8; ++j){
      int off = (j + 8) * 8 + sl;
      float pp0 = p_s[0][off], pp1 = p_s[1][off];
      a0.x += pp0 * vv1[j].x; a0.y += pp0 * vv1[j].y; a0.z += pp0 * vv1[j].z; a0.w += pp0 * vv1[j].w;
      a1.x += pp1 * vv1[j].x; a1.y += pp1 * vv1[j].y; a1.z += pp1 * vv1[j].z; a1.w += pp1 * vv1[j].w;
    }
    *(float4*)&part[0][sl][d4] = a0;
    *(float4*)&part[1][sl][d4] = a1;
  }
  __syncthreads();
  {
    int hh = t >> 7, d = t & 127;
    float o = 0.f;
    #pragma unroll
    for (int ss = 0; ss < 8; ++ss) o += part[hh][ss][d];
    int qh = kv * 2 + hh;
    opart[((size_t)qh * NCH + ch) * DH + d] = o;
  }
}

// ---- K4: combine chunk partials + new-token term. grid=HQ, 512 threads.
__global__ void k_combine(const float* __restrict__ opart,
                          const float2* __restrict__ ml,
                          const float* __restrict__ qf,
                          const float* __restrict__ kf,
                          const float* __restrict__ vnew,   // raw+3072: [HKV][DH]
                          const float* __restrict__ mask,
                          float* __restrict__ attn_in){
  __shared__ float osum[4][DH];
  __shared__ float Ls[4];
  __shared__ float redm[8];
  __shared__ float redq[2];
  int qh = blockIdx.x, t = threadIdx.x;
  int g = t >> 7, d = t & 127;
  int kv = qh >> 1;
  const float2* mlrow = ml + (size_t)qh * NCH;
  float mm = mlrow[t & 127].x;
  #pragma unroll
  for (int off = 32; off; off >>= 1) mm = fmaxf(mm, __shfl_down(mm, off, 64));
  if ((t & 63) == 0) redm[t >> 6] = mm;
  __syncthreads();
  float M = fmaxf(redm[0], redm[1]);
  float o = 0.f, L = 0.f;
  int ch0 = g * 32;
  #pragma unroll 4
  for (int i = 0; i < 32; ++i){
    float2 m2 = mlrow[ch0 + i];
    float w = __expf(m2.x - M);
    L += m2.y * w;
    o += w * opart[((size_t)qh * NCH + ch0 + i) * DH + d];
  }
  osum[g][d] = o;
  if (d == 0) Ls[g] = L;
  if (t < DH){
    float sum = qf[qh * DH + t] * kf[kv * DH + t];
    #pragma unroll
    for (int off = 32; off; off >>= 1) sum += __shfl_down(sum, off, 64);
    if ((t & 63) == 0) redq[t >> 6] = sum;
  }
  __syncthreads();
  if (t < DH){
    float s_new = (redq[0] + redq[1]) * 0.08838834764831845f + mask[CC];
    float pn = __expf(s_new - M);
    float Lf = Ls[0] + Ls[1] + Ls[2] + Ls[3] + pn;
    float of = osum[0][t] + osum[1][t] + osum[2][t] + osum[3][t]
             + pn * vnew[kv * DH + t];
    attn_in[qh * DH + t] = of / Lf;
  }
}

// ---- K5: o_proj GEMV. One wave per output element, 8-deep batched.
__global__ void k_oproj(const float* __restrict__ attn_in,
                        const float* __restrict__ Wo,
                        float* __restrict__ out){
  int wave = threadIdx.x >> 6, lane = threadIdx.x & 63;
  int e = blockIdx.x * 4 + wave;
  const float* W = Wo + (size_t)e * HID;
  float4 wb[8], xb[8];
  #pragma unroll
  for (int j = 0; j < 8; ++j) wb[j] = *(const float4*)(W + (j * 64 + lane) * 4);
  #pragma unroll
  for (int j = 0; j < 8; ++j) xb[j] = *(const float4*)(attn_in + (j * 64 + lane) * 4);
  float acc = 0.f;
  #pragma unroll
  for (int j = 0; j < 8; ++j)
    acc += wb[j].x*xb[j].x + wb[j].y*xb[j].y + wb[j].z*xb[j].z + wb[j].w*xb[j].w;
  #pragma unroll
  for (int off = 32; off; off >>= 1) acc += __shfl_down(acc, off, 64);
  if (lane == 0) out[e] = acc;
}

extern "C" void kernel_launch(void* const* d_in, const int* in_sizes, int n_in,
                              void* d_out, int out_size, void* d_ws, size_t ws_size,
                              hipStream_t stream){
  const float* x    = (const float*)d_in[0];
  const float* cosb = (const float*)d_in[1];
  const float* sinb = (const float*)d_in[2];
  const float* mask = (const float*)d_in[3];
  const float* kc   = (const float*)d_in[4];
  const float* vc   = (const float*)d_in[5];
  const float* Wq   = (const float*)d_in[6];
  const float* Wk   = (const float*)d_in[7];
  const float* Wv   = (const float*)d_in[8];
  const float* Wo   = (const float*)d_in[9];
  const float* qw   = (const float*)d_in[10];
  const float* kw   = (const float*)d_in[11];
  float* out = (float*)d_out;
  float* ws = (float*)d_ws;
  float* raw     = ws;                          // 4096
  float* qf      = ws + 4096;                   // 2048
  float* kf      = ws + 6144;                   // 1024
  float* opart   = ws + 8192;                   // 16*128*128 = 262144
  float2* ML     = (float2*)(ws + 270336);      // 16*128 float2 = 4096 floats
  float* attn_in = ws + 274432;                 // 2048

  k_qkv     <<<1024, 256, 0, stream>>>(x, Wq, Wk, Wv, raw, out);
  k_normrope<<<24,   128, 0, stream>>>(raw, cosb, sinb, qw, kw, qf, kf, out);
  k_flash   <<<HKV * NCH, 256, 0, stream>>>(qf, kc, vc, mask, opart, ML);
  k_combine <<<HQ, 512, 0, stream>>>(opart, ML, qf, kf, raw + 3072, mask, attn_in);
  k_oproj   <<<512, 256, 0, stream>>>(attn_in, Wo, out);
}

// Round 4
// 212.853 us; speedup vs baseline: 2.3030x; 1.0163x over previous
//
#include <hip/hip_runtime.h>
#include <math.h>
#include <stddef.h>

#define HQ   16
#define HKV  8
#define DH   128
#define HID  2048
#define CC   16384
#define NCH  32             // flash chunks of 512
#define CHUNK 512

// d_out layout (FLOAT32, 4096 elements): [attn 2048][k_new 8*128][v 8*128]

// ---- K1: QKV projections. One wave per output element.
__global__ void k_qkv(const float* __restrict__ x,
                      const float* __restrict__ Wq,
                      const float* __restrict__ Wk,
                      const float* __restrict__ Wv,
                      float* __restrict__ raw,
                      float* __restrict__ out){
  int wave = threadIdx.x >> 6, lane = threadIdx.x & 63;
  int e = blockIdx.x * 4 + wave;
  const float* W;
  if (e < 2048)      W = Wq + (size_t)e * HID;
  else if (e < 3072) W = Wk + (size_t)(e - 2048) * HID;
  else               W = Wv + (size_t)(e - 3072) * HID;
  float4 wb[8], xb[8];
  #pragma unroll
  for (int j = 0; j < 8; ++j) wb[j] = *(const float4*)(W + (j * 64 + lane) * 4);
  #pragma unroll
  for (int j = 0; j < 8; ++j) xb[j] = *(const float4*)(x + (j * 64 + lane) * 4);
  __builtin_amdgcn_sched_barrier(0);
  float acc = 0.f;
  #pragma unroll
  for (int j = 0; j < 8; ++j)
    acc += wb[j].x*xb[j].x + wb[j].y*xb[j].y + wb[j].z*xb[j].z + wb[j].w*xb[j].w;
  #pragma unroll
  for (int off = 32; off; off >>= 1) acc += __shfl_down(acc, off, 64);
  if (lane == 0){
    raw[e] = acc;
    if (e >= 3072) out[e] = acc;   // v passthrough
  }
}

// ---- K2: RMSNorm + RoPE (q,k). grid=24, 128 threads.
__global__ void k_normrope(const float* __restrict__ raw,
                           const float* __restrict__ cosb,
                           const float* __restrict__ sinb,
                           const float* __restrict__ qw,
                           const float* __restrict__ kw,
                           float* __restrict__ qf,
                           float* __restrict__ kf,
                           float* __restrict__ out){
  __shared__ float lds[DH];
  __shared__ float wsum[2];
  int b = blockIdx.x, t = threadIdx.x;
  bool isq = (b < 16);
  int h = isq ? b : b - 16;
  float val = isq ? raw[h * DH + t] : raw[2048 + h * DH + t];
  float ss = val * val;
  #pragma unroll
  for (int off = 32; off; off >>= 1) ss += __shfl_down(ss, off, 64);
  if ((t & 63) == 0) wsum[t >> 6] = ss;
  __syncthreads();
  float rms = sqrtf((wsum[0] + wsum[1]) / 128.f + 1e-6f);
  float w = isq ? qw[t] : kw[t];
  float normed = val / rms * w;
  lds[t] = normed;
  __syncthreads();
  float rot = (t < 64) ? -lds[t + 64] : lds[t - 64];
  float res = normed * cosb[t] + rot * sinb[t];
  if (isq) qf[h * DH + t] = res;
  else { kf[h * DH + t] = res; out[2048 + h * DH + t] = res; }
}

// ---- K3: flash-decode. grid = HKV*NCH = 256 blocks x 512 threads.
// CHUNK=512: K dim-row segments are 2 KB contiguous (was 512 B at 64 KB
// stride); V is a 256 KB contiguous stream per block. Load groups pinned
// with sched_barrier(0) so they truly issue in flight together.
__global__ __launch_bounds__(512) void k_flash(
    const float* __restrict__ qf,
    const float* __restrict__ kcache,  // [HKV][DH][CC]
    const float* __restrict__ vcache,  // [HKV][CC][DH]
    const float* __restrict__ mask,    // [CC+1]
    float* __restrict__ opart,         // [HQ][NCH][DH]
    float2* __restrict__ ml){          // [HQ][NCH]
  __shared__ float q_s[2][DH];
  __shared__ float sc_part[8][2][CHUNK];   // 32 KB
  __shared__ float p_s[2][CHUNK];          // 4 KB
  __shared__ float part[2][16][DH];        // 16 KB
  __shared__ float red[32];
  int kv = blockIdx.x >> 5, ch = blockIdx.x & 31;
  int c0 = ch << 9;                        // * CHUNK
  int t = threadIdx.x;
  if (t < 256) q_s[t >> 7][t & 127] = qf[(kv * 2 + (t >> 7)) * DH + (t & 127)];
  __syncthreads();
  const float scale = 0.08838834764831845f;  // 128^-0.5

  // ---- Phase A: QK^T. 8 d-groups x 64 lanes; each thread 4 positions x 2 halves.
  {
    int dg = t >> 6, ln = t & 63;
    const float* kp = kcache + (size_t)kv * DH * CC + (size_t)(dg * 16) * CC + c0 + ln * 4;
    float qr0[16], qr1[16];
    #pragma unroll
    for (int i = 0; i < 16; ++i){
      qr0[i] = q_s[0][dg * 16 + i];
      qr1[i] = q_s[1][dg * 16 + i];
    }
    #pragma unroll
    for (int half = 0; half < 2; ++half){
      const float* kph = kp + half * 256;
      float4 kb[8], kc2[8];
      #pragma unroll
      for (int j = 0; j < 8; ++j) kb[j]  = *(const float4*)(kph + (size_t)j * CC);
      #pragma unroll
      for (int j = 0; j < 8; ++j) kc2[j] = *(const float4*)(kph + (size_t)(j + 8) * CC);
      __builtin_amdgcn_sched_barrier(0);
      float a00 = 0.f, a01 = 0.f, a02 = 0.f, a03 = 0.f;
      float a10 = 0.f, a11 = 0.f, a12 = 0.f, a13 = 0.f;
      #pragma unroll
      for (int j = 0; j < 8; ++j){
        a00 += qr0[j] * kb[j].x;  a01 += qr0[j] * kb[j].y;
        a02 += qr0[j] * kb[j].z;  a03 += qr0[j] * kb[j].w;
        a10 += qr1[j] * kb[j].x;  a11 += qr1[j] * kb[j].y;
        a12 += qr1[j] * kb[j].z;  a13 += qr1[j] * kb[j].w;
      }
      #pragma unroll
      for (int j = 0; j < 8; ++j){
        a00 += qr0[8 + j] * kc2[j].x;  a01 += qr0[8 + j] * kc2[j].y;
        a02 += qr0[8 + j] * kc2[j].z;  a03 += qr0[8 + j] * kc2[j].w;
        a10 += qr1[8 + j] * kc2[j].x;  a11 += qr1[8 + j] * kc2[j].y;
        a12 += qr1[8 + j] * kc2[j].z;  a13 += qr1[8 + j] * kc2[j].w;
      }
      *(float4*)&sc_part[dg][0][half * 256 + ln * 4] = make_float4(a00, a01, a02, a03);
      *(float4*)&sc_part[dg][1][half * 256 + ln * 4] = make_float4(a10, a11, a12, a13);
    }
  }
  __syncthreads();

  // ---- Phase B: combine partials, chunk softmax. Thread t <-> position t.
  int wv = t >> 6;
  float s0, s1;
  {
    float acc0 = 0.f, acc1 = 0.f;
    #pragma unroll
    for (int dg = 0; dg < 8; ++dg){
      acc0 += sc_part[dg][0][t];
      acc1 += sc_part[dg][1][t];
    }
    float mk = mask[c0 + t];
    s0 = acc0 * scale + mk;
    s1 = acc1 * scale + mk;
  }
  float lm0 = s0, lm1 = s1;
  #pragma unroll
  for (int off = 32; off; off >>= 1){
    lm0 = fmaxf(lm0, __shfl_down(lm0, off, 64));
    lm1 = fmaxf(lm1, __shfl_down(lm1, off, 64));
  }
  if ((t & 63) == 0){ red[wv] = lm0; red[8 + wv] = lm1; }
  __syncthreads();
  float m0 = red[0], m1 = red[8];
  #pragma unroll
  for (int i = 1; i < 8; ++i){
    m0 = fmaxf(m0, red[i]);
    m1 = fmaxf(m1, red[8 + i]);
  }
  float p0 = __expf(s0 - m0);
  float p1 = __expf(s1 - m1);
  p_s[0][t] = p0;
  p_s[1][t] = p1;
  float ls0 = p0, ls1 = p1;
  #pragma unroll
  for (int off = 32; off; off >>= 1){
    ls0 += __shfl_down(ls0, off, 64);
    ls1 += __shfl_down(ls1, off, 64);
  }
  if ((t & 63) == 0){ red[16 + wv] = ls0; red[24 + wv] = ls1; }
  __syncthreads();
  if (t == 0){
    float l0 = 0.f, l1 = 0.f;
    #pragma unroll
    for (int i = 0; i < 8; ++i){ l0 += red[16 + i]; l1 += red[24 + i]; }
    ml[(size_t)(kv * 2)     * NCH + ch] = make_float2(m0, l0);
    ml[(size_t)(kv * 2 + 1) * NCH + ch] = make_float2(m1, l1);
  }

  // ---- Phase C: partial O. 16 pos-slices x 32 dim-lanes; 8-deep pinned batches.
  {
    int sl = t >> 5, d4 = (t & 31) * 4;
    const float* vbase = vcache + (size_t)kv * CC * DH + (size_t)c0 * DH + d4;
    float4 a0 = make_float4(0.f, 0.f, 0.f, 0.f);
    float4 a1 = make_float4(0.f, 0.f, 0.f, 0.f);
    #pragma unroll
    for (int ib = 0; ib < 4; ++ib){
      float4 vv[8];
      #pragma unroll
      for (int j = 0; j < 8; ++j){
        int off = (ib * 8 + j) * 16 + sl;
        vv[j] = *(const float4*)(vbase + (size_t)off * DH);
      }
      __builtin_amdgcn_sched_barrier(0);
      #pragma unroll
      for (int j = 0; j < 8; ++j){
        int off = (ib * 8 + j) * 16 + sl;
        float pp0 = p_s[0][off], pp1 = p_s[1][off];
        a0.x += pp0 * vv[j].x; a0.y += pp0 * vv[j].y; a0.z += pp0 * vv[j].z; a0.w += pp0 * vv[j].w;
        a1.x += pp1 * vv[j].x; a1.y += pp1 * vv[j].y; a1.z += pp1 * vv[j].z; a1.w += pp1 * vv[j].w;
      }
    }
    *(float4*)&part[0][sl][d4] = a0;
    *(float4*)&part[1][sl][d4] = a1;
  }
  __syncthreads();
  if (t < 256){
    int hh = t >> 7, d = t & 127;
    float o = 0.f;
    #pragma unroll
    for (int ss = 0; ss < 16; ++ss) o += part[hh][ss][d];
    int qh = kv * 2 + hh;
    opart[((size_t)qh * NCH + ch) * DH + d] = o;
  }
}

// ---- K4: combine chunk partials + new-token term. grid=HQ, 512 threads.
__global__ void k_combine(const float* __restrict__ opart,
                          const float2* __restrict__ ml,
                          const float* __restrict__ qf,
                          const float* __restrict__ kf,
                          const float* __restrict__ vnew,   // raw+3072: [HKV][DH]
                          const float* __restrict__ mask,
                          float* __restrict__ attn_in){
  __shared__ float osum[4][DH];
  __shared__ float Ls[4];
  __shared__ float redm[8];
  __shared__ float redq[2];
  int qh = blockIdx.x, t = threadIdx.x;
  int g = t >> 7, d = t & 127;
  int kv = qh >> 1;
  const float2* mlrow = ml + (size_t)qh * NCH;
  float mm = mlrow[t & 31].x;     // every wave covers all 32 chunks (dup x2)
  #pragma unroll
  for (int off = 32; off; off >>= 1) mm = fmaxf(mm, __shfl_down(mm, off, 64));
  if ((t & 63) == 0) redm[t >> 6] = mm;
  __syncthreads();
  float M = fmaxf(redm[0], redm[1]);
  float o = 0.f, L = 0.f;
  int ch0 = g * 8;
  #pragma unroll
  for (int i = 0; i < 8; ++i){
    float2 m2 = mlrow[ch0 + i];
    float w = __expf(m2.x - M);
    L += m2.y * w;
    o += w * opart[((size_t)qh * NCH + ch0 + i) * DH + d];
  }
  osum[g][d] = o;
  if (d == 0) Ls[g] = L;
  if (t < DH){
    float sum = qf[qh * DH + t] * kf[kv * DH + t];
    #pragma unroll
    for (int off = 32; off; off >>= 1) sum += __shfl_down(sum, off, 64);
    if ((t & 63) == 0) redq[t >> 6] = sum;
  }
  __syncthreads();
  if (t < DH){
    float s_new = (redq[0] + redq[1]) * 0.08838834764831845f + mask[CC];
    float pn = __expf(s_new - M);
    float Lf = Ls[0] + Ls[1] + Ls[2] + Ls[3] + pn;
    float of = osum[0][t] + osum[1][t] + osum[2][t] + osum[3][t]
             + pn * vnew[kv * DH + t];
    attn_in[qh * DH + t] = of / Lf;
  }
}

// ---- K5: o_proj GEMV. One wave per output element, pinned 8-deep batch.
__global__ void k_oproj(const float* __restrict__ attn_in,
                        const float* __restrict__ Wo,
                        float* __restrict__ out){
  int wave = threadIdx.x >> 6, lane = threadIdx.x & 63;
  int e = blockIdx.x * 4 + wave;
  const float* W = Wo + (size_t)e * HID;
  float4 wb[8], xb[8];
  #pragma unroll
  for (int j = 0; j < 8; ++j) wb[j] = *(const float4*)(W + (j * 64 + lane) * 4);
  #pragma unroll
  for (int j = 0; j < 8; ++j) xb[j] = *(const float4*)(attn_in + (j * 64 + lane) * 4);
  __builtin_amdgcn_sched_barrier(0);
  float acc = 0.f;
  #pragma unroll
  for (int j = 0; j < 8; ++j)
    acc += wb[j].x*xb[j].x + wb[j].y*xb[j].y + wb[j].z*xb[j].z + wb[j].w*xb[j].w;
  #pragma unroll
  for (int off = 32; off; off >>= 1) acc += __shfl_down(acc, off, 64);
  if (lane == 0) out[e] = acc;
}

extern "C" void kernel_launch(void* const* d_in, const int* in_sizes, int n_in,
                              void* d_out, int out_size, void* d_ws, size_t ws_size,
                              hipStream_t stream){
  const float* x    = (const float*)d_in[0];
  const float* cosb = (const float*)d_in[1];
  const float* sinb = (const float*)d_in[2];
  const float* mask = (const float*)d_in[3];
  const float* kc   = (const float*)d_in[4];
  const float* vc   = (const float*)d_in[5];
  const float* Wq   = (const float*)d_in[6];
  const float* Wk   = (const float*)d_in[7];
  const float* Wv   = (const float*)d_in[8];
  const float* Wo   = (const float*)d_in[9];
  const float* qw   = (const float*)d_in[10];
  const float* kw   = (const float*)d_in[11];
  float* out = (float*)d_out;
  float* ws = (float*)d_ws;
  float* raw     = ws;                          // 4096
  float* qf      = ws + 4096;                   // 2048
  float* kf      = ws + 6144;                   // 1024
  float* opart   = ws + 8192;                   // 16*32*128 = 65536
  float2* ML     = (float2*)(ws + 73728);       // 16*32 float2 = 1024 floats
  float* attn_in = ws + 74752;                  // 2048

  k_qkv     <<<1024, 256, 0, stream>>>(x, Wq, Wk, Wv, raw, out);
  k_normrope<<<24,   128, 0, stream>>>(raw, cosb, sinb, qw, kw, qf, kf, out);
  k_flash   <<<HKV * NCH, 512, 0, stream>>>(qf, kc, vc, mask, opart, ML);
  k_combine <<<HQ, 512, 0, stream>>>(opart, ML, qf, kf, raw + 3072, mask, attn_in);
  k_oproj   <<<512, 256, 0, stream>>>(attn_in, Wo, out);
}